// Round 23
// baseline (234.454 us; speedup 1.0000x reference)
//
#include <hip/hip_runtime.h>

// SelfAttention: out = softmax((xWq)(xWk)^T/32) @ (xWv), f32, S=4096, D=1024.
// R23: k_pvs retiled to 64x128 blocks (grid 512 = 2 blocks/CU resident for
// cross-block TLP), 2 bufs x 24KB (+4KB scale) = 52KB LDS, quad K-split
// (tile 2p+qd -> buf qd), stage pair p+1 after end-of-pair barrier.
// Rest = R22: k_qkt BK=64 1-MFMA + deferred softmax; rank-1 decomposition.
// ws (MiB): xh 0, xl 8 (r/p/q overlay), Th 16, Vt 32, Pt 40..72,
//   mtile 72, tsum 73; temps in dead-Pt: Wqh 40.., Mth 48, Wtvh 52, sa/sb 54.

typedef _Float16 f16;
typedef f16 f16x8 __attribute__((ext_vector_type(8)));
typedef f16 f16x4v __attribute__((ext_vector_type(4)));
typedef float f32x4 __attribute__((ext_vector_type(4)));
typedef float f32x16 __attribute__((ext_vector_type(16)));
typedef unsigned short u16;
typedef u16 u16x8 __attribute__((ext_vector_type(8)));

extern __shared__ char dsm[];  // single dynamic-LDS symbol for the whole TU

__device__ __forceinline__ void split_f32(float v, f16& h, f16& l) {
  h = (f16)v;
  l = (f16)(v - (float)h);
}

__device__ __forceinline__ void gload16(const void* g, void* l) {
  __builtin_amdgcn_global_load_lds(
      (const __attribute__((address_space(1))) void*)g,
      (__attribute__((address_space(3))) void*)l, 16, 0, 0);
}

// ---- merged prep ----
__global__ __launch_bounds__(256) void k_prep(
    const float* __restrict__ x, const float* __restrict__ Wq,
    const float* __restrict__ Wk, const float* __restrict__ Wv,
    f16* __restrict__ xh, f16* __restrict__ xl, f16* __restrict__ wqh,
    f16* __restrict__ wql, f16* __restrict__ wkh, f16* __restrict__ wkl,
    f16* __restrict__ wvt, float* __restrict__ sa, float* __restrict__ sb) {
  const int y = blockIdx.y;
  if (y <= 2) {
    const float* __restrict__ src = (y == 0) ? x : (y == 1) ? Wq : Wk;
    f16* __restrict__ oh = (y == 0) ? xh : (y == 1) ? wqh : wkh;
    f16* __restrict__ ol = (y == 0) ? xl : (y == 1) ? wql : wkl;
    const int n4 = (y == 0) ? (4096 * 1024 / 4) : (1024 * 1024 / 4);
    for (int i = blockIdx.x * 256 + threadIdx.x; i < n4; i += 1024 * 256) {
      float4 f = ((const float4*)src)[i];
      f16x4v h, l;
      f16 hh, ll;
      split_f32(f.x, hh, ll); h[0] = hh; l[0] = ll;
      split_f32(f.y, hh, ll); h[1] = hh; l[1] = ll;
      split_f32(f.z, hh, ll); h[2] = hh; l[2] = ll;
      split_f32(f.w, hh, ll); h[3] = hh; l[3] = ll;
      ((f16x4v*)oh)[i] = h;
      ((f16x4v*)ol)[i] = l;
    }
  } else if (y == 3) {
    if (blockIdx.x >= 256) return;
    __shared__ float sh[64][65];
    const int kb = (blockIdx.x >> 4) * 64, nb = (blockIdx.x & 15) * 64;
    const int t = threadIdx.x;
    const int r = t >> 2, c4 = (t & 3) * 16;
#pragma unroll
    for (int i = 0; i < 4; ++i) {
      float4 f = *(const float4*)&Wv[(size_t)(kb + r) * 1024 + nb + c4 + i * 4];
      sh[r][c4 + i * 4 + 0] = f.x;
      sh[r][c4 + i * 4 + 1] = f.y;
      sh[r][c4 + i * 4 + 2] = f.z;
      sh[r][c4 + i * 4 + 3] = f.w;
    }
    __syncthreads();
    const int n = t >> 2, ks = (t & 3) * 16;
    u16x8 h0, h1;
#pragma unroll
    for (int i = 0; i < 8; ++i) {
      h0[i] = __builtin_bit_cast(u16, (f16)sh[ks + i][n]);
      h1[i] = __builtin_bit_cast(u16, (f16)sh[ks + 8 + i][n]);
    }
    const size_t o = (size_t)(nb + n) * 1024 + kb + ks;
    *(u16x8*)&wvt[o] = h0;
    *(u16x8*)&wvt[o + 8] = h1;
  } else {
    if (blockIdx.x >= 512) return;
    const int z = blockIdx.x >> 8;
    const float* __restrict__ W = z ? Wk : Wq;
    float* __restrict__ o = z ? sb : sa;
    const int row = (blockIdx.x & 255) * 4 + (threadIdx.x >> 6);
    const int lane = threadIdx.x & 63;
    const float4* src = (const float4*)(W + (size_t)row * 1024);
    float s = 0.f;
#pragma unroll
    for (int i = 0; i < 4; ++i) {
      float4 f = src[lane + 64 * i];
      s += f.x + f.y + f.z + f.w;
    }
#pragma unroll
    for (int off = 1; off < 64; off <<= 1) s += __shfl_xor(s, off, 64);
    if (lane == 0) o[row] = s - 512.0f;
  }
}

// ---- prep: r = x*1, p = x*sa, q = x*sb ----
__global__ __launch_bounds__(256) void k_rpq(
    const float* __restrict__ x, const float* __restrict__ sa,
    const float* __restrict__ sb, float* __restrict__ rv,
    float* __restrict__ pv, float* __restrict__ qv) {
  const int row = blockIdx.x * 4 + (threadIdx.x >> 6);
  const int lane = threadIdx.x & 63;
  const float* xr = x + (size_t)row * 1024;
  float sr = 0.f, sp = 0.f, sq = 0.f;
#pragma unroll
  for (int i = 0; i < 4; ++i) {
    const int c = (lane + 64 * i) * 4;
    float4 f = *(const float4*)&xr[c];
    float4 a = *(const float4*)&sa[c];
    float4 b = *(const float4*)&sb[c];
    sr += f.x + f.y + f.z + f.w;
    sp += f.x * a.x + f.y * a.y + f.z * a.z + f.w * a.w;
    sq += f.x * b.x + f.y * b.y + f.z * b.z + f.w * b.w;
  }
#pragma unroll
  for (int off = 1; off < 64; off <<= 1) {
    sr += __shfl_xor(sr, off, 64);
    sp += __shfl_xor(sp, off, 64);
    sq += __shfl_xor(sq, off, 64);
  }
  if (lane == 0) {
    rv[row] = sr;
    pv[row] = sp;
    qv[row] = sq;
  }
}

// ---- S-residual (1-MFMA) + deferred softmax; BK=64, 2x64KB buffers ----
__global__ __launch_bounds__(512, 1) void k_qkt(
    const f16* __restrict__ Ah, const f16* __restrict__ Bx,
    const float* __restrict__ rv, const float* __restrict__ pv,
    const float* __restrict__ qv, f16* __restrict__ Pt,
    float* __restrict__ mtile, float* __restrict__ tsum) {
  char* smem = dsm;
  constexpr int K = 1024, N = 4096, nT = 16, BUF = 65536;
  const int tid = threadIdx.x;
  const int lane = tid & 63, wv = tid >> 6;
  const int bid = blockIdx.x;
  const int wg = (bid & 7) * 32 + (bid >> 3);
  const int bx = wg >> 4, by = wg & 15;
  const int brow = bx * 256, bcol = by * 256;

  const int srow8 = lane >> 3;
  const int scol8 = lane & 7;

  auto stageh = [&](int buf, int t, int half) {
    const int kt = t * 64;
    char* bb = smem + BUF * buf;
#pragma unroll
    for (int j = 0; j < 4; ++j) {
      const int g = wv * 8 + half * 4 + j;
      const int rg = g >> 5, gm = g & 31;
      const int r = gm * 8 + srow8;
      const f16* base = rg ? Bx : Ah;
      const int rowb = rg ? bcol : brow;
      const int sc = scol8 ^ ((r >> 1) & 7);
      gload16(base + (size_t)(rowb + r) * K + kt + 8 * sc,
              bb + rg * 32768 + gm * 1024);
    }
  };

  f32x16 acc[8] = {};
  const int l31 = lane & 31, ch0 = lane >> 5;
  const int arow = wv * 32 + l31;

  stageh(0, 0, 0);
  stageh(0, 0, 1);

  for (int t = 0; t < nT; ++t) {
    const int cur = t & 1;
    const char* bb = smem + BUF * cur;
    const bool pre = t < nT - 1;
    if (pre) {
      stageh(cur ^ 1, t + 1, 0);
      __builtin_amdgcn_sched_barrier(0);
      asm volatile("s_waitcnt vmcnt(4)" ::: "memory");
    } else {
      asm volatile("s_waitcnt vmcnt(0)" ::: "memory");
    }
    __builtin_amdgcn_sched_barrier(0);
    __builtin_amdgcn_s_barrier();
    __builtin_amdgcn_sched_barrier(0);

#pragma unroll
    for (int ks = 0; ks < 4; ++ks) {
      const int ch = ks * 2 + ch0;
      f16x8 a_h, b_h[8];
      a_h = *(const f16x8*)(bb + arow * 128 + 16 * (ch ^ ((arow >> 1) & 7)));
#pragma unroll
      for (int fn = 0; fn < 8; ++fn) {
        const int r = fn * 32 + l31;
        b_h[fn] = *(const f16x8*)(bb + 32768 + r * 128 +
                                  16 * (ch ^ ((r >> 1) & 7)));
      }
      if (ks == 1 && pre) stageh(cur ^ 1, t + 1, 1);
      asm volatile("s_waitcnt lgkmcnt(0)" ::: "memory");
      __builtin_amdgcn_sched_barrier(0);
      __builtin_amdgcn_s_setprio(1);
#pragma unroll
      for (int fn = 0; fn < 8; ++fn)
        acc[fn] = __builtin_amdgcn_mfma_f32_32x32x16_f16(a_h, b_h[fn], acc[fn],
                                                         0, 0, 0);
      __builtin_amdgcn_s_setprio(0);
    }
    __builtin_amdgcn_sched_barrier(0);
    __builtin_amdgcn_s_barrier();
  }

  float rc[8], qc[8];
#pragma unroll
  for (int fn = 0; fn < 8; ++fn) {
    const int col = bcol + fn * 32 + l31;
    rc[fn] = rv[col];
    qc[fn] = qv[col];
  }
  const int rowbase = brow + wv * 32;
#pragma unroll
  for (int j = 0; j < 16; ++j) {
    const int rl = (j & 3) + 8 * (j >> 2) + 4 * ch0;
    const int row = rowbase + rl;
    const float rr = rv[row], pr = pv[row];
    float s[8];
    float m = -3.4e38f;
#pragma unroll
    for (int fn = 0; fn < 8; ++fn) {
      s[fn] = acc[fn][j] + 8.0f * rr * rc[fn] + (pr * rc[fn] + rr * qc[fn]) * 0.015625f;
      m = fmaxf(m, s[fn]);
    }
#pragma unroll
    for (int off = 1; off < 32; off <<= 1) m = fmaxf(m, __shfl_xor(m, off, 64));
    float sm = 0.f;
#pragma unroll
    for (int fn = 0; fn < 8; ++fn) {
      const float e = __expf(s[fn] - m);
      sm += e;
      Pt[(size_t)row * N + bcol + fn * 32 + l31] = (f16)e;
    }
#pragma unroll
    for (int off = 1; off < 32; off <<= 1) sm += __shfl_xor(sm, off, 64);
    if (l31 == 0) {
      mtile[row * 16 + by] = m;
      tsum[row * 16 + by] = sm;
    }
  }
}

// ---- PV: 64x128 block (grid 512 = 2 blocks/CU), 2 K-split quads of 2x2
// waves (32x64 each), BK=64, 2 bufs x 24KB (tile 2p+qd -> buf qd), scale
// folded per 256-col chunk. Buf: P[0,8K) 64 rows, V[8K,24K) 128 rows;
// 128B rows, slot swizzle ^=(row>>1)&7.
__global__ __launch_bounds__(512, 2) void k_pvs(const f16* __restrict__ P,
                                                const f16* __restrict__ Vt,
                                                const float* __restrict__ mtile,
                                                const float* __restrict__ tsum,
                                                float* __restrict__ out) {
  char* smem = dsm;
  constexpr int K = 4096, BUF = 24576, NP = 32;
  const int tid = threadIdx.x;
  const int lane = tid & 63, wv = tid >> 6;
  const int qd = wv >> 2, wq = wv & 3;
  const int wr = wq >> 1, wc = wq & 1;  // wave tile 32x64
  const int bid = blockIdx.x;                  // 512 blocks
  const int wg = (bid & 7) * 64 + (bid >> 3);  // bijective XCD swizzle
  const int bx = wg >> 3, by = wg & 7;         // 64 x 8
  const int brow = bx * 64, bcol = by * 128;

  // preamble: per-block scale slice [16][64]
  float* sc_lds = (float*)(smem + 2 * BUF);
  if (tid < 64) {
    const int row = brow + tid;
    float mt[16], ts[16];
    float m = -3.4e38f;
#pragma unroll
    for (int t4 = 0; t4 < 4; ++t4) {
      float4 v = *(const float4*)&mtile[row * 16 + t4 * 4];
      float4 w = *(const float4*)&tsum[row * 16 + t4 * 4];
      mt[t4 * 4 + 0] = v.x; mt[t4 * 4 + 1] = v.y;
      mt[t4 * 4 + 2] = v.z; mt[t4 * 4 + 3] = v.w;
      ts[t4 * 4 + 0] = w.x; ts[t4 * 4 + 1] = w.y;
      ts[t4 * 4 + 2] = w.z; ts[t4 * 4 + 3] = w.w;
      m = fmaxf(m, fmaxf(fmaxf(v.x, v.y), fmaxf(v.z, v.w)));
    }
    float sum = 0.f;
#pragma unroll
    for (int t = 0; t < 16; ++t) sum += ts[t] * __expf(mt[t] - m);
    const float inv = 1.0f / sum;
#pragma unroll
    for (int t = 0; t < 16; ++t)
      sc_lds[t * 64 + tid] = __expf(mt[t] - m) * inv;
  }
  __syncthreads();

  const int srow8 = lane >> 3;
  const int scol8 = lane & 7;

  // stage one BK=64 tile: 24 groups of 1KB (P g=0..7, V g=8..23); 3/wave
  auto stage = [&](int t) {
    const int kt = t * 64;
    char* bb = smem + BUF * (t & 1);
#pragma unroll
    for (int j = 0; j < 3; ++j) {
      const int g = wv * 3 + j;
      const bool isv = g >= 8;
      const int gm = isv ? g - 8 : g;
      const int r = gm * 8 + srow8;
      const f16* base = isv ? Vt : P;
      const int rowb = isv ? bcol : brow;
      const int sc = scol8 ^ ((r >> 1) & 7);
      gload16(base + (size_t)(rowb + r) * K + kt + 8 * sc, bb + g * 1024);
    }
  };

  f32x16 accp[2] = {};
  f32x16 accf[2] = {};
  const int l31 = lane & 31, ch0 = lane >> 5;
  const int ar0 = wr * 32 + l31;  // P row (single fm)
  const int br0 = wc * 64 + l31;  // + fn*32 (V row)

  stage(0);
  stage(1);

  for (int p = 0; p < NP; ++p) {
    asm volatile("s_waitcnt vmcnt(0)" ::: "memory");  // pair p landed (mine)
    __builtin_amdgcn_sched_barrier(0);
    __builtin_amdgcn_s_barrier();  // all waves' staging landed
    __builtin_amdgcn_sched_barrier(0);
    const char* bb = smem + BUF * qd;  // tile 2p+qd
#pragma unroll
    for (int ks = 0; ks < 4; ++ks) {
      const int ch = ks * 2 + ch0;
      f16x8 a, b[2];
      a = *(const f16x8*)(bb + ar0 * 128 + 16 * (ch ^ ((ar0 >> 1) & 7)));
#pragma unroll
      for (int fn = 0; fn < 2; ++fn) {
        const int r = br0 + fn * 32;
        b[fn] = *(const f16x8*)(bb + 8192 + r * 128 +
                                16 * (ch ^ ((r >> 1) & 7)));
      }
      asm volatile("s_waitcnt lgkmcnt(0)" ::: "memory");
      __builtin_amdgcn_sched_barrier(0);
      __builtin_amdgcn_s_setprio(1);
#pragma unroll
      for (int fn = 0; fn < 2; ++fn)
        accp[fn] = __builtin_amdgcn_mfma_f32_32x32x16_f16(a, b[fn], accp[fn],
                                                          0, 0, 0);
      __builtin_amdgcn_s_setprio(0);
    }
    if (p & 1) {  // fold chunk tc (tiles 4tc..4tc+3 across both quads)
      const int tc = p >> 1;
#pragma unroll
      for (int fn = 0; fn < 2; ++fn)
#pragma unroll
        for (int j = 0; j < 16; ++j) {
          const int rloc = wr * 32 + (j & 3) + 8 * (j >> 2) + 4 * ch0;
          accf[fn][j] += sc_lds[tc * 64 + rloc] * accp[fn][j];
          accp[fn][j] = 0.0f;
        }
    }
    __builtin_amdgcn_sched_barrier(0);
    __builtin_amdgcn_s_barrier();  // all reads of bufs drained (WAR)
    if (p < NP - 1) {
      stage(2 * p + 2);
      stage(2 * p + 3);
    }
  }

  // quad reduction: quad1 -> LDS, quad0 adds + stores
  float* red = (float*)smem;
  if (qd == 1) {
#pragma unroll
    for (int fn = 0; fn < 2; ++fn)
#pragma unroll
      for (int j = 0; j < 16; ++j)
        red[wq * 2048 + fn * 1024 + j * 64 + lane] = accf[fn][j];
  }
  __syncthreads();
  if (qd == 0) {
#pragma unroll
    for (int fn = 0; fn < 2; ++fn)
#pragma unroll
      for (int j = 0; j < 16; ++j) {
        const float v =
            accf[fn][j] + red[wq * 2048 + fn * 1024 + j * 64 + lane];
        const int row = brow + wr * 32 + (j & 3) + 8 * (j >> 2) + 4 * ch0;
        const int col = bcol + wc * 64 + fn * 32 + l31;
        out[(size_t)row * 1024 + col] = v;
      }
  }
}

// ---- depth-3 pipelined BT-GEMM (Vt): C = A . B^T, f16 out ----
template <int K, int NBY>
__global__ __launch_bounds__(512, 1) void pipe_bt(const f16* __restrict__ A,
                                                  const f16* __restrict__ B,
                                                  f16* __restrict__ outh,
                                                  int ldo) {
  char* smem = dsm;
  constexpr int nT = K / 32, BUF = 16384;
  const int tid = threadIdx.x;
  const int lane = tid & 63, wv = tid >> 6;
  const int wm = wv >> 2, wn = wv & 3;
  const int bid = blockIdx.x;
  const int wg = (bid & 7) * 32 + (bid >> 3);
  const int bx = wg / NBY, by = wg % NBY;
  const int brow = bx * 128, bcol = by * 128;

  const int srow16 = lane >> 2;
  const int sslot = (lane & 3) ^ ((lane >> 3) & 3);
  const int sreg = wv >> 2;
  const f16* __restrict__ sbase = sreg ? B : A;
  const int rbase = sreg ? bcol : brow;

  auto stage = [&](int buf, int t) {
    const int kt = t * 32;
    char* bb = smem + BUF * buf + sreg * 8192;
#pragma unroll
    for (int j = 0; j < 2; ++j) {
      const int g = (wv & 3) * 2 + j;
      gload16(sbase + (size_t)(rbase + g * 16 + srow16) * K + kt + 8 * sslot,
              bb + g * 1024);
    }
  };

  f32x16 acc[2] = {};
  const int l31 = lane & 31, ch0 = lane >> 5;
  const int arow0 = wm * 64 + l31;
  const int brow0 = wn * 32 + l31;

  stage(0, 0);
  stage(1, 1);
  stage(2, 2);

  for (int t = 0; t < nT; ++t) {
    const int rem = nT - 1 - t;
    if (rem >= 3) stage((t + 3) & 3, t + 3);
    __builtin_amdgcn_sched_barrier(0);
    if (rem >= 3) {
      asm volatile("s_waitcnt vmcnt(6)" ::: "memory");
    } else if (rem == 2) {
      asm volatile("s_waitcnt vmcnt(4)" ::: "memory");
    } else if (rem == 1) {
      asm volatile("s_waitcnt vmcnt(2)" ::: "memory");
    } else {
      asm volatile("s_waitcnt vmcnt(0)" ::: "memory");
    }
    __builtin_amdgcn_sched_barrier(0);
    __builtin_amdgcn_s_barrier();
    __builtin_amdgcn_sched_barrier(0);
    const char* bb = smem + BUF * (t & 3);
#pragma unroll
    for (int ks = 0; ks < 2; ++ks) {
      const int ch = ks * 2 + ch0;
      f16x8 a_h[2], b_h;
#pragma unroll
      for (int fm = 0; fm < 2; ++fm) {
        const int r = arow0 + fm * 32;
        a_h[fm] = *(const f16x8*)(bb + r * 64 + 16 * (ch ^ ((r >> 1) & 3)));
      }
      b_h = *(const f16x8*)(bb + 8192 + brow0 * 64 +
                            16 * (ch ^ ((brow0 >> 1) & 3)));
      __builtin_amdgcn_sched_barrier(0);
      asm volatile("s_waitcnt lgkmcnt(0)" ::: "memory");
      __builtin_amdgcn_sched_barrier(0);
      __builtin_amdgcn_s_setprio(1);
#pragma unroll
      for (int fm = 0; fm < 2; ++fm)
        acc[fm] = __builtin_amdgcn_mfma_f32_32x32x16_f16(a_h[fm], b_h, acc[fm],
                                                         0, 0, 0);
      __builtin_amdgcn_s_setprio(0);
      __builtin_amdgcn_sched_barrier(0);
    }
    __builtin_amdgcn_s_barrier();
  }

#pragma unroll
  for (int fm = 0; fm < 2; ++fm) {
    const int col = bcol + wn * 32 + l31;
#pragma unroll
    for (int j = 0; j < 16; ++j) {
      const int row =
          brow + wm * 64 + fm * 32 + (j & 3) + 8 * (j >> 2) + 4 * ch0;
      outh[(size_t)row * ldo + col] = (f16)acc[fm][j];
    }
  }
}

// ---- generic BT-GEMM (m97-style) ----
template <int NM, int OUT>
__global__ __launch_bounds__(256) void gemm_bt(
    const f16* __restrict__ A, const f16* __restrict__ Al,
    const f16* __restrict__ B, const f16* __restrict__ Bl, int K,
    f16* __restrict__ oh, f16* __restrict__ ol, int ldo, float scale,
    const float* __restrict__ sav, const float* __restrict__ sbv) {
  f16* smem = (f16*)dsm;
  f16* tAh = smem;
  f16* tBh = smem + 8192;
  f16* tAl = smem + 16384;
  f16* tBl = smem + 24576;

  const int tid = threadIdx.x;
  const int lane = tid & 63, wid = tid >> 6;
  const int wr = wid >> 1, wc = wid & 1;
  const int brow = blockIdx.x * 128, bcol = blockIdx.y * 128;
  const int ar = lane & 15, k0 = (lane >> 4) * 8;
  const int crow = lane >> 3, ccol = (lane & 7) * 8;

  f32x4 acc[4][4] = {};
  const size_t aoff = (size_t)crow * K + ccol;

  for (int kt = 0; kt < K; kt += 64) {
    const f16* Ab = A + (size_t)brow * K + kt;
    const f16* Bb = B + (size_t)bcol * K + kt;
#pragma unroll
    for (int cc = 0; cc < 4; ++cc) {
      const int c = wid * 4 + cc;
      const size_t co = (size_t)c * 8 * K + aoff;
      gload16(Ab + co, tAh + c * 512);
      gload16(Bb + co, tBh + c * 512);
      if constexpr (NM >= 2) gload16(Al + (size_t)brow * K + kt + co, tAl + c * 512);
      if constexpr (NM == 3) gload16(Bl + (size_t)bcol * K + kt + co, tBl + c * 512);
    }
    __syncthreads();
#pragma unroll
    for (int ks = 0; ks < 2; ++ks) {
      f16x8 ah[4], bh[4], alv[4], blv[4];
#pragma unroll
      for (int m = 0; m < 4; ++m) {
        ah[m] = *(const f16x8*)&tAh[(wr * 64 + m * 16 + ar) * 64 + ks * 32 + k0];
        bh[m] = *(const f16x8*)&tBh[(wc * 64 + m * 16 + ar) * 64 + ks * 32 + k0];
        if constexpr (NM >= 2)
          alv[m] = *(const f16x8*)&tAl[(wr * 64 + m * 16 + ar) * 64 + ks * 32 + k0];
        if constexpr (NM == 3)
          blv[m] = *(const f16x8*)&tBl[(wc * 64 + m * 16 + ar) * 64 + ks * 32 + k0];
      }
#pragma unroll
      for (int m = 0; m < 4; ++m)
#pragma unroll
        for (int n = 0; n < 4; ++n) {
          acc[m][n] = __builtin_amdgcn_mfma_f32_16x16x32_f16(ah[m], bh[n], acc[m][n], 0, 0, 0);
          if constexpr (NM >= 2)
            acc[m][n] = __builtin_amdgcn_mfma_f32_16x16x32_f16(alv[m], bh[n], acc[m][n], 0, 0, 0);
          if constexpr (NM == 3)
            acc[m][n] = __builtin_amdgcn_mfma_f32_16x16x32_f16(ah[m], blv[n], acc[m][n], 0, 0, 0);
        }
    }
    __syncthreads();
  }

#pragma unroll
  for (int m = 0; m < 4; ++m)
#pragma unroll
    for (int n = 0; n < 4; ++n)
#pragma unroll
      for (int j = 0; j < 4; ++j) {
        const int row = brow + wr * 64 + m * 16 + (lane >> 4) * 4 + j;
        const int col = bcol + wc * 64 + n * 16 + ar;
        const size_t idx = (size_t)row * ldo + col;
        if constexpr (OUT == 1) {
          f16 h, l;
          split_f32(acc[m][n][j] * scale, h, l);
          oh[idx] = h;
          ol[idx] = l;
        } else if constexpr (OUT == 2) {
          oh[idx] = (f16)(acc[m][n][j] * scale);
        } else {  // OUT == 4
          const float v =
              (acc[m][n][j] - 256.0f - 0.5f * sav[col] - 0.5f * sbv[row]) * scale;
          oh[idx] = (f16)v;
        }
      }
}

extern "C" void kernel_launch(void* const* d_in, const int* in_sizes, int n_in,
                              void* d_out, int out_size, void* d_ws,
                              size_t ws_size, hipStream_t stream) {
  const float* x = (const float*)d_in[0];
  const float* Wq = (const float*)d_in[1];
  const float* Wk = (const float*)d_in[2];
  const float* Wv = (const float*)d_in[3];
  float* out = (float*)d_out;
  char* ws = (char*)d_ws;
  const size_t MiB = 1u << 20;
  f16* xh = (f16*)(ws + 0 * MiB);
  f16* xl = (f16*)(ws + 8 * MiB);
  f16* Th = (f16*)(ws + 16 * MiB);
  f16* Vt = (f16*)(ws + 32 * MiB);
  f16* Pt = (f16*)(ws + 40 * MiB);
  float* mtile = (float*)(ws + 72 * MiB);
  float* tsum = (float*)(ws + 73 * MiB);
  f16* Wqh = (f16*)(ws + 40 * MiB);
  f16* Wql = (f16*)(ws + 42 * MiB);
  f16* Wkh = (f16*)(ws + 44 * MiB);
  f16* Wkl = (f16*)(ws + 46 * MiB);
  f16* Mth = (f16*)(ws + 48 * MiB);
  f16* Wtvh = (f16*)(ws + 52 * MiB);
  float* sa = (float*)(ws + 54 * MiB);
  float* sb = (float*)(ws + 54 * MiB + 65536);
  float* rv = (float*)(ws + 8 * MiB);
  float* pv = (float*)(ws + 8 * MiB + 65536);
  float* qv = (float*)(ws + 8 * MiB + 131072);

  (void)hipFuncSetAttribute((const void*)k_qkt,
                            hipFuncAttributeMaxDynamicSharedMemorySize, 131072);
  (void)hipFuncSetAttribute((const void*)k_pvs,
                            hipFuncAttributeMaxDynamicSharedMemorySize, 53248);
  (void)hipFuncSetAttribute((const void*)pipe_bt<1024, 32>,
                            hipFuncAttributeMaxDynamicSharedMemorySize, 65536);

  k_prep<<<dim3(1024, 5), 256, 0, stream>>>(x, Wq, Wk, Wv, xh, xl, Wqh, Wql,
                                            Wkh, Wkl, Wtvh, sa, sb);
  gemm_bt<3, 4><<<dim3(8, 8), 256, 65536, stream>>>(
      Wkh, Wkl, Wqh, Wql, 1024, Mth, nullptr, 1024, 0.03125f, sa, sb);
  gemm_bt<2, 2><<<dim3(32, 8), 256, 49152, stream>>>(
      xh, xl, Mth, nullptr, 1024, Th, nullptr, 1024, 1.0f, nullptr, nullptr);
  pipe_bt<1024, 32><<<dim3(256), 512, 65536, stream>>>(Wtvh, xh, Vt, 4096);
  k_rpq<<<dim3(1024), 256, 0, stream>>>(x, sa, sb, rv, pv, qv);
  k_qkt<<<dim3(256), 512, 131072, stream>>>(Th, xh, rv, pv, qv, Pt, mtile,
                                            tsum);
  k_pvs<<<dim3(512), 512, 53248, stream>>>(Pt, Vt, mtile, tsum, out);
}

// Round 24
// 197.287 us; speedup vs baseline: 1.1884x; 1.1884x over previous
//
#include <hip/hip_runtime.h>

// SelfAttention: out = softmax((xWq)(xWk)^T/32) @ (xWv), f32, S=4096, D=1024.
// R24 = R22 exact (best measured: 197.2us). R23's k_pvs retile regressed
// (Vt refetch doubled + no prefetch overlap) and is reverted.
// k_qkt: BK=64, 2x64KB bufs, 1-MFMA + deferred softmax epilogue.
// k_pvs: 128x128, 2 K-split quads, BK=64, 4x32KB bufs, scale folded.
// scores = 8rr^T+(pr^T+rq^T)/64+Th·xh^T (rank-1 decomposition of W_qW_k^T).
// ws (MiB): xh 0, xl 8 (r/p/q overlay), Th 16, Vt 32, Pt 40..72,
//   mtile 72, tsum 73; temps in dead-Pt: Wqh 40.., Mth 48, Wtvh 52, sa/sb 54.

typedef _Float16 f16;
typedef f16 f16x8 __attribute__((ext_vector_type(8)));
typedef f16 f16x4v __attribute__((ext_vector_type(4)));
typedef float f32x4 __attribute__((ext_vector_type(4)));
typedef float f32x16 __attribute__((ext_vector_type(16)));
typedef unsigned short u16;
typedef u16 u16x8 __attribute__((ext_vector_type(8)));

extern __shared__ char dsm[];  // single dynamic-LDS symbol for the whole TU

__device__ __forceinline__ void split_f32(float v, f16& h, f16& l) {
  h = (f16)v;
  l = (f16)(v - (float)h);
}

__device__ __forceinline__ void gload16(const void* g, void* l) {
  __builtin_amdgcn_global_load_lds(
      (const __attribute__((address_space(1))) void*)g,
      (__attribute__((address_space(3))) void*)l, 16, 0, 0);
}

// ---- merged prep: y=0 split x; y=1 split Wq; y=2 split Wk; y=3 Wv^T f16;
// y=4 rowsums. Grid-stride for splits. ----
__global__ __launch_bounds__(256) void k_prep(
    const float* __restrict__ x, const float* __restrict__ Wq,
    const float* __restrict__ Wk, const float* __restrict__ Wv,
    f16* __restrict__ xh, f16* __restrict__ xl, f16* __restrict__ wqh,
    f16* __restrict__ wql, f16* __restrict__ wkh, f16* __restrict__ wkl,
    f16* __restrict__ wvt, float* __restrict__ sa, float* __restrict__ sb) {
  const int y = blockIdx.y;
  if (y <= 2) {
    const float* __restrict__ src = (y == 0) ? x : (y == 1) ? Wq : Wk;
    f16* __restrict__ oh = (y == 0) ? xh : (y == 1) ? wqh : wkh;
    f16* __restrict__ ol = (y == 0) ? xl : (y == 1) ? wql : wkl;
    const int n4 = (y == 0) ? (4096 * 1024 / 4) : (1024 * 1024 / 4);
    for (int i = blockIdx.x * 256 + threadIdx.x; i < n4; i += 1024 * 256) {
      float4 f = ((const float4*)src)[i];
      f16x4v h, l;
      f16 hh, ll;
      split_f32(f.x, hh, ll); h[0] = hh; l[0] = ll;
      split_f32(f.y, hh, ll); h[1] = hh; l[1] = ll;
      split_f32(f.z, hh, ll); h[2] = hh; l[2] = ll;
      split_f32(f.w, hh, ll); h[3] = hh; l[3] = ll;
      ((f16x4v*)oh)[i] = h;
      ((f16x4v*)ol)[i] = l;
    }
  } else if (y == 3) {
    if (blockIdx.x >= 256) return;
    __shared__ float sh[64][65];
    const int kb = (blockIdx.x >> 4) * 64, nb = (blockIdx.x & 15) * 64;
    const int t = threadIdx.x;
    const int r = t >> 2, c4 = (t & 3) * 16;
#pragma unroll
    for (int i = 0; i < 4; ++i) {
      float4 f = *(const float4*)&Wv[(size_t)(kb + r) * 1024 + nb + c4 + i * 4];
      sh[r][c4 + i * 4 + 0] = f.x;
      sh[r][c4 + i * 4 + 1] = f.y;
      sh[r][c4 + i * 4 + 2] = f.z;
      sh[r][c4 + i * 4 + 3] = f.w;
    }
    __syncthreads();
    const int n = t >> 2, ks = (t & 3) * 16;
    u16x8 h0, h1;
#pragma unroll
    for (int i = 0; i < 8; ++i) {
      h0[i] = __builtin_bit_cast(u16, (f16)sh[ks + i][n]);
      h1[i] = __builtin_bit_cast(u16, (f16)sh[ks + 8 + i][n]);
    }
    const size_t o = (size_t)(nb + n) * 1024 + kb + ks;
    *(u16x8*)&wvt[o] = h0;
    *(u16x8*)&wvt[o + 8] = h1;
  } else {
    if (blockIdx.x >= 512) return;
    const int z = blockIdx.x >> 8;
    const float* __restrict__ W = z ? Wk : Wq;
    float* __restrict__ o = z ? sb : sa;
    const int row = (blockIdx.x & 255) * 4 + (threadIdx.x >> 6);
    const int lane = threadIdx.x & 63;
    const float4* src = (const float4*)(W + (size_t)row * 1024);
    float s = 0.f;
#pragma unroll
    for (int i = 0; i < 4; ++i) {
      float4 f = src[lane + 64 * i];
      s += f.x + f.y + f.z + f.w;
    }
#pragma unroll
    for (int off = 1; off < 64; off <<= 1) s += __shfl_xor(s, off, 64);
    if (lane == 0) o[row] = s - 512.0f;
  }
}

// ---- prep: r = x*1, p = x*sa, q = x*sb ----
__global__ __launch_bounds__(256) void k_rpq(
    const float* __restrict__ x, const float* __restrict__ sa,
    const float* __restrict__ sb, float* __restrict__ rv,
    float* __restrict__ pv, float* __restrict__ qv) {
  const int row = blockIdx.x * 4 + (threadIdx.x >> 6);
  const int lane = threadIdx.x & 63;
  const float* xr = x + (size_t)row * 1024;
  float sr = 0.f, sp = 0.f, sq = 0.f;
#pragma unroll
  for (int i = 0; i < 4; ++i) {
    const int c = (lane + 64 * i) * 4;
    float4 f = *(const float4*)&xr[c];
    float4 a = *(const float4*)&sa[c];
    float4 b = *(const float4*)&sb[c];
    sr += f.x + f.y + f.z + f.w;
    sp += f.x * a.x + f.y * a.y + f.z * a.z + f.w * a.w;
    sq += f.x * b.x + f.y * b.y + f.z * b.z + f.w * b.w;
  }
#pragma unroll
  for (int off = 1; off < 64; off <<= 1) {
    sr += __shfl_xor(sr, off, 64);
    sp += __shfl_xor(sp, off, 64);
    sq += __shfl_xor(sq, off, 64);
  }
  if (lane == 0) {
    rv[row] = sr;
    pv[row] = sp;
    qv[row] = sq;
  }
}

// ---- S-residual (1-MFMA) + deferred softmax; BK=64, 2x64KB buffers ----
// 256x256 tile, waves own 32 rows x 256 cols. Rows of 128B, 8 slots of 16B,
// slot swizzle ^= (row>>1)&7 (inverse on global src + swizzled read).
__global__ __launch_bounds__(512, 1) void k_qkt(
    const f16* __restrict__ Ah, const f16* __restrict__ Bx,
    const float* __restrict__ rv, const float* __restrict__ pv,
    const float* __restrict__ qv, f16* __restrict__ Pt,
    float* __restrict__ mtile, float* __restrict__ tsum) {
  char* smem = dsm;
  constexpr int K = 1024, N = 4096, nT = 16, BUF = 65536;
  const int tid = threadIdx.x;
  const int lane = tid & 63, wv = tid >> 6;
  const int bid = blockIdx.x;
  const int wg = (bid & 7) * 32 + (bid >> 3);
  const int bx = wg >> 4, by = wg & 15;
  const int brow = bx * 256, bcol = by * 256;

  const int srow8 = lane >> 3;  // row within 8-row group
  const int scol8 = lane & 7;   // 16B slot index

  // 64 groups of 1 KiB (A g=0..31, B g=32..63); wave stages g=wv*8+half*4+j
  auto stageh = [&](int buf, int t, int half) {
    const int kt = t * 64;
    char* bb = smem + BUF * buf;
#pragma unroll
    for (int j = 0; j < 4; ++j) {
      const int g = wv * 8 + half * 4 + j;
      const int rg = g >> 5, gm = g & 31;
      const int r = gm * 8 + srow8;
      const f16* base = rg ? Bx : Ah;
      const int rowb = rg ? bcol : brow;
      const int sc = scol8 ^ ((r >> 1) & 7);
      gload16(base + (size_t)(rowb + r) * K + kt + 8 * sc,
              bb + rg * 32768 + gm * 1024);
    }
  };

  f32x16 acc[8] = {};  // [fn] — wave owns rows wv*32..+31, all 256 cols
  const int l31 = lane & 31, ch0 = lane >> 5;
  const int arow = wv * 32 + l31;

  stageh(0, 0, 0);
  stageh(0, 0, 1);

  for (int t = 0; t < nT; ++t) {
    const int cur = t & 1;
    const char* bb = smem + BUF * cur;
    const bool pre = t < nT - 1;
    if (pre) {
      stageh(cur ^ 1, t + 1, 0);
      __builtin_amdgcn_sched_barrier(0);
      asm volatile("s_waitcnt vmcnt(4)" ::: "memory");  // tile t's 8 landed
    } else {
      asm volatile("s_waitcnt vmcnt(0)" ::: "memory");
    }
    __builtin_amdgcn_sched_barrier(0);
    __builtin_amdgcn_s_barrier();  // RAW: tile t staging landed (all waves)
    __builtin_amdgcn_sched_barrier(0);

#pragma unroll
    for (int ks = 0; ks < 4; ++ks) {
      const int ch = ks * 2 + ch0;
      f16x8 a_h, b_h[8];
      a_h = *(const f16x8*)(bb + arow * 128 + 16 * (ch ^ ((arow >> 1) & 7)));
#pragma unroll
      for (int fn = 0; fn < 8; ++fn) {
        const int r = fn * 32 + l31;
        b_h[fn] = *(const f16x8*)(bb + 32768 + r * 128 +
                                  16 * (ch ^ ((r >> 1) & 7)));
      }
      if (ks == 1 && pre) stageh(cur ^ 1, t + 1, 1);
      asm volatile("s_waitcnt lgkmcnt(0)" ::: "memory");
      __builtin_amdgcn_sched_barrier(0);
      __builtin_amdgcn_s_setprio(1);
#pragma unroll
      for (int fn = 0; fn < 8; ++fn)
        acc[fn] = __builtin_amdgcn_mfma_f32_32x32x16_f16(a_h, b_h[fn], acc[fn],
                                                         0, 0, 0);
      __builtin_amdgcn_s_setprio(0);
    }
    __builtin_amdgcn_sched_barrier(0);
    __builtin_amdgcn_s_barrier();  // WAR: buf cur reads drained before t+2 stage
  }

  // ---- epilogue (wave-local): rank-1 add, row max/sum, Pt = exp(s-m) ----
  float rc[8], qc[8];
#pragma unroll
  for (int fn = 0; fn < 8; ++fn) {
    const int col = bcol + fn * 32 + l31;
    rc[fn] = rv[col];
    qc[fn] = qv[col];
  }
  const int rowbase = brow + wv * 32;
#pragma unroll
  for (int j = 0; j < 16; ++j) {
    const int rl = (j & 3) + 8 * (j >> 2) + 4 * ch0;
    const int row = rowbase + rl;
    const float rr = rv[row], pr = pv[row];
    float s[8];
    float m = -3.4e38f;
#pragma unroll
    for (int fn = 0; fn < 8; ++fn) {
      s[fn] = acc[fn][j] + 8.0f * rr * rc[fn] + (pr * rc[fn] + rr * qc[fn]) * 0.015625f;
      m = fmaxf(m, s[fn]);
    }
#pragma unroll
    for (int off = 1; off < 32; off <<= 1) m = fmaxf(m, __shfl_xor(m, off, 64));
    float sm = 0.f;
#pragma unroll
    for (int fn = 0; fn < 8; ++fn) {
      const float e = __expf(s[fn] - m);
      sm += e;
      Pt[(size_t)row * N + bcol + fn * 32 + l31] = (f16)e;
    }
#pragma unroll
    for (int off = 1; off < 32; off <<= 1) sm += __shfl_xor(sm, off, 64);
    if (l31 == 0) {
      mtile[row * 16 + by] = m;
      tsum[row * 16 + by] = sm;
    }
  }
}

// ---- PV: 128x128 block, 2 K-split quads of 2x2 waves (64x64 each),
// BK=64, 4x32KB buffers (tile t -> buf t&3), scale folded per 256-col chunk.
__global__ __launch_bounds__(512, 2) void k_pvs(const f16* __restrict__ P,
                                                const f16* __restrict__ Vt,
                                                const float* __restrict__ mtile,
                                                const float* __restrict__ tsum,
                                                float* __restrict__ out) {
  char* smem = dsm;
  constexpr int K = 4096, BUF = 32768, NP = 32;
  const int tid = threadIdx.x;
  const int lane = tid & 63, wv = tid >> 6;
  const int qd = wv >> 2, wq = wv & 3;
  const int wr = wq >> 1, wc = wq & 1;
  const int bid = blockIdx.x;
  const int wg = (bid & 7) * 32 + (bid >> 3);
  const int bx = wg >> 3, by = wg & 7;
  const int brow = bx * 128, bcol = by * 128;

  float* sc_lds = (float*)(smem + 4 * BUF);
  if (tid < 128) {
    const int row = brow + tid;
    float mt[16], ts[16];
    float m = -3.4e38f;
#pragma unroll
    for (int t4 = 0; t4 < 4; ++t4) {
      float4 v = *(const float4*)&mtile[row * 16 + t4 * 4];
      float4 w = *(const float4*)&tsum[row * 16 + t4 * 4];
      mt[t4 * 4 + 0] = v.x; mt[t4 * 4 + 1] = v.y;
      mt[t4 * 4 + 2] = v.z; mt[t4 * 4 + 3] = v.w;
      ts[t4 * 4 + 0] = w.x; ts[t4 * 4 + 1] = w.y;
      ts[t4 * 4 + 2] = w.z; ts[t4 * 4 + 3] = w.w;
      m = fmaxf(m, fmaxf(fmaxf(v.x, v.y), fmaxf(v.z, v.w)));
    }
    float sum = 0.f;
#pragma unroll
    for (int t = 0; t < 16; ++t) sum += ts[t] * __expf(mt[t] - m);
    const float inv = 1.0f / sum;
#pragma unroll
    for (int t = 0; t < 16; ++t)
      sc_lds[t * 128 + tid] = __expf(mt[t] - m) * inv;
  }
  __syncthreads();

  const int srow8 = lane >> 3;
  const int scol8 = lane & 7;

  auto stage = [&](int t) {
    const int kt = t * 64;
    char* bb = smem + BUF * (t & 3);
#pragma unroll
    for (int j = 0; j < 4; ++j) {
      const int g = wv * 4 + j;
      const int rg = g >> 4, gm = g & 15;
      const int r = gm * 8 + srow8;
      const f16* base = rg ? Vt : P;
      const int rowb = rg ? bcol : brow;
      const int sc = scol8 ^ ((r >> 1) & 7);
      gload16(base + (size_t)(rowb + r) * K + kt + 8 * sc,
              bb + rg * 16384 + gm * 1024);
    }
  };

  f32x16 accp[2][2] = {};
  f32x16 accf[2][2] = {};
  const int l31 = lane & 31, ch0 = lane >> 5;
  const int ar0 = wr * 64 + l31;
  const int br0 = wc * 64 + l31;

  stage(0);
  stage(1);

  for (int p = 0; p < NP; ++p) {
    const bool pre = p < NP - 1;
    if (pre) {
      stage(2 * p + 2);
      __builtin_amdgcn_sched_barrier(0);
      asm volatile("s_waitcnt vmcnt(4)" ::: "memory");
    } else {
      asm volatile("s_waitcnt vmcnt(0)" ::: "memory");
    }
    __builtin_amdgcn_sched_barrier(0);
    __builtin_amdgcn_s_barrier();
    __builtin_amdgcn_sched_barrier(0);
    const char* bb = smem + BUF * ((2 * p + qd) & 3);
#pragma unroll
    for (int ks = 0; ks < 4; ++ks) {
      const int ch = ks * 2 + ch0;
      f16x8 a[2], b[2];
#pragma unroll
      for (int fm = 0; fm < 2; ++fm) {
        const int r = ar0 + fm * 32;
        a[fm] = *(const f16x8*)(bb + r * 128 + 16 * (ch ^ ((r >> 1) & 7)));
      }
#pragma unroll
      for (int fn = 0; fn < 2; ++fn) {
        const int r = br0 + fn * 32;
        b[fn] = *(const f16x8*)(bb + 16384 + r * 128 +
                                16 * (ch ^ ((r >> 1) & 7)));
      }
      if (ks == 0 && pre) stage(2 * p + 3);
      asm volatile("s_waitcnt lgkmcnt(0)" ::: "memory");
      __builtin_amdgcn_sched_barrier(0);
      __builtin_amdgcn_s_setprio(1);
#pragma unroll
      for (int fm = 0; fm < 2; ++fm)
#pragma unroll
        for (int fn = 0; fn < 2; ++fn)
          accp[fm][fn] = __builtin_amdgcn_mfma_f32_32x32x16_f16(
              a[fm], b[fn], accp[fm][fn], 0, 0, 0);
      __builtin_amdgcn_s_setprio(0);
    }
    if (p & 1) {
      const int tc = p >> 1;
#pragma unroll
      for (int fm = 0; fm < 2; ++fm)
#pragma unroll
        for (int fn = 0; fn < 2; ++fn)
#pragma unroll
          for (int j = 0; j < 16; ++j) {
            const int rloc =
                wr * 64 + fm * 32 + (j & 3) + 8 * (j >> 2) + 4 * ch0;
            accf[fm][fn][j] += sc_lds[tc * 128 + rloc] * accp[fm][fn][j];
            accp[fm][fn][j] = 0.0f;
          }
    }
    __builtin_amdgcn_sched_barrier(0);
    __builtin_amdgcn_s_barrier();
  }

  float* red = (float*)smem;
  if (qd == 1) {
#pragma unroll
    for (int fm = 0; fm < 2; ++fm)
#pragma unroll
      for (int fn = 0; fn < 2; ++fn)
#pragma unroll
        for (int j = 0; j < 16; ++j)
          red[wq * 4096 + (fm * 2 + fn) * 1024 + j * 64 + lane] =
              accf[fm][fn][j];
  }
  __syncthreads();
  if (qd == 0) {
#pragma unroll
    for (int fm = 0; fm < 2; ++fm)
#pragma unroll
      for (int fn = 0; fn < 2; ++fn)
#pragma unroll
        for (int j = 0; j < 16; ++j) {
          const float v = accf[fm][fn][j] +
                          red[wq * 4096 + (fm * 2 + fn) * 1024 + j * 64 + lane];
          const int row =
              brow + wr * 64 + fm * 32 + (j & 3) + 8 * (j >> 2) + 4 * ch0;
          const int col = bcol + wc * 64 + fn * 32 + l31;
          out[(size_t)row * 1024 + col] = v;
        }
  }
}

// ---- depth-3 pipelined BT-GEMM (Vt): C = A . B^T, f16 out ----
template <int K, int NBY>
__global__ __launch_bounds__(512, 1) void pipe_bt(const f16* __restrict__ A,
                                                  const f16* __restrict__ B,
                                                  f16* __restrict__ outh,
                                                  int ldo) {
  char* smem = dsm;
  constexpr int nT = K / 32, BUF = 16384;
  const int tid = threadIdx.x;
  const int lane = tid & 63, wv = tid >> 6;
  const int wm = wv >> 2, wn = wv & 3;
  const int bid = blockIdx.x;
  const int wg = (bid & 7) * 32 + (bid >> 3);
  const int bx = wg / NBY, by = wg % NBY;
  const int brow = bx * 128, bcol = by * 128;

  const int srow16 = lane >> 2;
  const int sslot = (lane & 3) ^ ((lane >> 3) & 3);
  const int sreg = wv >> 2;
  const f16* __restrict__ sbase = sreg ? B : A;
  const int rbase = sreg ? bcol : brow;

  auto stage = [&](int buf, int t) {
    const int kt = t * 32;
    char* bb = smem + BUF * buf + sreg * 8192;
#pragma unroll
    for (int j = 0; j < 2; ++j) {
      const int g = (wv & 3) * 2 + j;
      gload16(sbase + (size_t)(rbase + g * 16 + srow16) * K + kt + 8 * sslot,
              bb + g * 1024);
    }
  };

  f32x16 acc[2] = {};
  const int l31 = lane & 31, ch0 = lane >> 5;
  const int arow0 = wm * 64 + l31;
  const int brow0 = wn * 32 + l31;

  stage(0, 0);
  stage(1, 1);
  stage(2, 2);

  for (int t = 0; t < nT; ++t) {
    const int rem = nT - 1 - t;
    if (rem >= 3) stage((t + 3) & 3, t + 3);
    __builtin_amdgcn_sched_barrier(0);
    if (rem >= 3) {
      asm volatile("s_waitcnt vmcnt(6)" ::: "memory");
    } else if (rem == 2) {
      asm volatile("s_waitcnt vmcnt(4)" ::: "memory");
    } else if (rem == 1) {
      asm volatile("s_waitcnt vmcnt(2)" ::: "memory");
    } else {
      asm volatile("s_waitcnt vmcnt(0)" ::: "memory");
    }
    __builtin_amdgcn_sched_barrier(0);
    __builtin_amdgcn_s_barrier();
    __builtin_amdgcn_sched_barrier(0);
    const char* bb = smem + BUF * (t & 3);
#pragma unroll
    for (int ks = 0; ks < 2; ++ks) {
      const int ch = ks * 2 + ch0;
      f16x8 a_h[2], b_h;
#pragma unroll
      for (int fm = 0; fm < 2; ++fm) {
        const int r = arow0 + fm * 32;
        a_h[fm] = *(const f16x8*)(bb + r * 64 + 16 * (ch ^ ((r >> 1) & 3)));
      }
      b_h = *(const f16x8*)(bb + 8192 + brow0 * 64 +
                            16 * (ch ^ ((brow0 >> 1) & 3)));
      __builtin_amdgcn_sched_barrier(0);
      asm volatile("s_waitcnt lgkmcnt(0)" ::: "memory");
      __builtin_amdgcn_sched_barrier(0);
      __builtin_amdgcn_s_setprio(1);
#pragma unroll
      for (int fm = 0; fm < 2; ++fm)
        acc[fm] = __builtin_amdgcn_mfma_f32_32x32x16_f16(a_h[fm], b_h, acc[fm],
                                                         0, 0, 0);
      __builtin_amdgcn_s_setprio(0);
      __builtin_amdgcn_sched_barrier(0);
    }
    __builtin_amdgcn_s_barrier();
  }

#pragma unroll
  for (int fm = 0; fm < 2; ++fm) {
    const int col = bcol + wn * 32 + l31;
#pragma unroll
    for (int j = 0; j < 16; ++j) {
      const int row =
          brow + wm * 64 + fm * 32 + (j & 3) + 8 * (j >> 2) + 4 * ch0;
      outh[(size_t)row * ldo + col] = (f16)acc[fm][j];
    }
  }
}

// ---- generic BT-GEMM (m97-style) ----
template <int NM, int OUT>
__global__ __launch_bounds__(256) void gemm_bt(
    const f16* __restrict__ A, const f16* __restrict__ Al,
    const f16* __restrict__ B, const f16* __restrict__ Bl, int K,
    f16* __restrict__ oh, f16* __restrict__ ol, int ldo, float scale,
    const float* __restrict__ sav, const float* __restrict__ sbv) {
  f16* smem = (f16*)dsm;
  f16* tAh = smem;
  f16* tBh = smem + 8192;
  f16* tAl = smem + 16384;
  f16* tBl = smem + 24576;

  const int tid = threadIdx.x;
  const int lane = tid & 63, wid = tid >> 6;
  const int wr = wid >> 1, wc = wid & 1;
  const int brow = blockIdx.x * 128, bcol = blockIdx.y * 128;
  const int ar = lane & 15, k0 = (lane >> 4) * 8;
  const int crow = lane >> 3, ccol = (lane & 7) * 8;

  f32x4 acc[4][4] = {};
  const size_t aoff = (size_t)crow * K + ccol;

  for (int kt = 0; kt < K; kt += 64) {
    const f16* Ab = A + (size_t)brow * K + kt;
    const f16* Bb = B + (size_t)bcol * K + kt;
#pragma unroll
    for (int cc = 0; cc < 4; ++cc) {
      const int c = wid * 4 + cc;
      const size_t co = (size_t)c * 8 * K + aoff;
      gload16(Ab + co, tAh + c * 512);
      gload16(Bb + co, tBh + c * 512);
      if constexpr (NM >= 2) gload16(Al + (size_t)brow * K + kt + co, tAl + c * 512);
      if constexpr (NM == 3) gload16(Bl + (size_t)bcol * K + kt + co, tBl + c * 512);
    }
    __syncthreads();
#pragma unroll
    for (int ks = 0; ks < 2; ++ks) {
      f16x8 ah[4], bh[4], alv[4], blv[4];
#pragma unroll
      for (int m = 0; m < 4; ++m) {
        ah[m] = *(const f16x8*)&tAh[(wr * 64 + m * 16 + ar) * 64 + ks * 32 + k0];
        bh[m] = *(const f16x8*)&tBh[(wc * 64 + m * 16 + ar) * 64 + ks * 32 + k0];
        if constexpr (NM >= 2)
          alv[m] = *(const f16x8*)&tAl[(wr * 64 + m * 16 + ar) * 64 + ks * 32 + k0];
        if constexpr (NM == 3)
          blv[m] = *(const f16x8*)&tBl[(wc * 64 + m * 16 + ar) * 64 + ks * 32 + k0];
      }
#pragma unroll
      for (int m = 0; m < 4; ++m)
#pragma unroll
        for (int n = 0; n < 4; ++n) {
          acc[m][n] = __builtin_amdgcn_mfma_f32_16x16x32_f16(ah[m], bh[n], acc[m][n], 0, 0, 0);
          if constexpr (NM >= 2)
            acc[m][n] = __builtin_amdgcn_mfma_f32_16x16x32_f16(alv[m], bh[n], acc[m][n], 0, 0, 0);
          if constexpr (NM == 3)
            acc[m][n] = __builtin_amdgcn_mfma_f32_16x16x32_f16(ah[m], blv[n], acc[m][n], 0, 0, 0);
        }
    }
    __syncthreads();
  }

#pragma unroll
  for (int m = 0; m < 4; ++m)
#pragma unroll
    for (int n = 0; n < 4; ++n)
#pragma unroll
      for (int j = 0; j < 4; ++j) {
        const int row = brow + wr * 64 + m * 16 + (lane >> 4) * 4 + j;
        const int col = bcol + wc * 64 + n * 16 + ar;
        const size_t idx = (size_t)row * ldo + col;
        if constexpr (OUT == 1) {
          f16 h, l;
          split_f32(acc[m][n][j] * scale, h, l);
          oh[idx] = h;
          ol[idx] = l;
        } else if constexpr (OUT == 2) {
          oh[idx] = (f16)(acc[m][n][j] * scale);
        } else {  // OUT == 4
          const float v =
              (acc[m][n][j] - 256.0f - 0.5f * sav[col] - 0.5f * sbv[row]) * scale;
          oh[idx] = (f16)v;
        }
      }
}

extern "C" void kernel_launch(void* const* d_in, const int* in_sizes, int n_in,
                              void* d_out, int out_size, void* d_ws,
                              size_t ws_size, hipStream_t stream) {
  const float* x = (const float*)d_in[0];
  const float* Wq = (const float*)d_in[1];
  const float* Wk = (const float*)d_in[2];
  const float* Wv = (const float*)d_in[3];
  float* out = (float*)d_out;
  char* ws = (char*)d_ws;
  const size_t MiB = 1u << 20;
  f16* xh = (f16*)(ws + 0 * MiB);
  f16* xl = (f16*)(ws + 8 * MiB);
  f16* Th = (f16*)(ws + 16 * MiB);
  f16* Vt = (f16*)(ws + 32 * MiB);
  f16* Pt = (f16*)(ws + 40 * MiB);
  float* mtile = (float*)(ws + 72 * MiB);
  float* tsum = (float*)(ws + 73 * MiB);
  f16* Wqh = (f16*)(ws + 40 * MiB);
  f16* Wql = (f16*)(ws + 42 * MiB);
  f16* Wkh = (f16*)(ws + 44 * MiB);
  f16* Wkl = (f16*)(ws + 46 * MiB);
  f16* Mth = (f16*)(ws + 48 * MiB);
  f16* Wtvh = (f16*)(ws + 52 * MiB);
  float* sa = (float*)(ws + 54 * MiB);
  float* sb = (float*)(ws + 54 * MiB + 65536);
  float* rv = (float*)(ws + 8 * MiB);
  float* pv = (float*)(ws + 8 * MiB + 65536);
  float* qv = (float*)(ws + 8 * MiB + 131072);

  (void)hipFuncSetAttribute((const void*)k_qkt,
                            hipFuncAttributeMaxDynamicSharedMemorySize, 131072);
  (void)hipFuncSetAttribute((const void*)k_pvs,
                            hipFuncAttributeMaxDynamicSharedMemorySize, 139264);
  (void)hipFuncSetAttribute((const void*)pipe_bt<1024, 32>,
                            hipFuncAttributeMaxDynamicSharedMemorySize, 65536);

  k_prep<<<dim3(1024, 5), 256, 0, stream>>>(x, Wq, Wk, Wv, xh, xl, Wqh, Wql,
                                            Wkh, Wkl, Wtvh, sa, sb);
  gemm_bt<3, 4><<<dim3(8, 8), 256, 65536, stream>>>(
      Wkh, Wkl, Wqh, Wql, 1024, Mth, nullptr, 1024, 0.03125f, sa, sb);
  gemm_bt<2, 2><<<dim3(32, 8), 256, 49152, stream>>>(
      xh, xl, Mth, nullptr, 1024, Th, nullptr, 1024, 1.0f, nullptr, nullptr);
  pipe_bt<1024, 32><<<dim3(256), 512, 65536, stream>>>(Wtvh, xh, Vt, 4096);
  k_rpq<<<dim3(1024), 256, 0, stream>>>(x, sa, sb, rv, pv, qv);
  k_qkt<<<dim3(256), 512, 131072, stream>>>(Th, xh, rv, pv, qv, Pt, mtile,
                                            tsum);
  k_pvs<<<dim3(256), 512, 139264, stream>>>(Pt, Vt, mtile, tsum, out);
}

// Round 25
// 180.245 us; speedup vs baseline: 1.3008x; 1.0946x over previous
//
#include <hip/hip_runtime.h>

// SelfAttention: out = softmax((xWq)(xWk)^T/32) @ (xWv), f32, S=4096, D=1024.
// R25: T-GEMM made 1-MFMA (drop xl·Mres: rms 6.4e-4 < Th's own f16 quant
// noise 1.3e-3) and ported to the proven BK=64 pipelined structure (k_tg,
// 128x128, 4 waves, 2x32KB bufs, 2 blocks/CU). xl no longer stored.
// Rest = R24 (best: 197.3us). scores = 8rr^T+(pr^T+rq^T)/64+Th·xh^T.
// ws (MiB): xh 0, (r/p/q overlay 8), Th 16, Vt 32, Pt 40..72, mtile 72,
//   tsum 73; temps in dead-Pt: Wqh 40.., Mth 48, Wtvh 52, sa/sb 54.

typedef _Float16 f16;
typedef f16 f16x8 __attribute__((ext_vector_type(8)));
typedef f16 f16x4v __attribute__((ext_vector_type(4)));
typedef float f32x4 __attribute__((ext_vector_type(4)));
typedef float f32x16 __attribute__((ext_vector_type(16)));
typedef unsigned short u16;
typedef u16 u16x8 __attribute__((ext_vector_type(8)));

extern __shared__ char dsm[];  // single dynamic-LDS symbol for the whole TU

__device__ __forceinline__ void split_f32(float v, f16& h, f16& l) {
  h = (f16)v;
  l = (f16)(v - (float)h);
}

__device__ __forceinline__ void gload16(const void* g, void* l) {
  __builtin_amdgcn_global_load_lds(
      (const __attribute__((address_space(1))) void*)g,
      (__attribute__((address_space(3))) void*)l, 16, 0, 0);
}

// ---- merged prep: y=0 split x (h only); y=1 split Wq; y=2 split Wk;
// y=3 Wv^T f16; y=4 rowsums. Grid-stride for splits. ----
__global__ __launch_bounds__(256) void k_prep(
    const float* __restrict__ x, const float* __restrict__ Wq,
    const float* __restrict__ Wk, const float* __restrict__ Wv,
    f16* __restrict__ xh, f16* __restrict__ wqh, f16* __restrict__ wql,
    f16* __restrict__ wkh, f16* __restrict__ wkl, f16* __restrict__ wvt,
    float* __restrict__ sa, float* __restrict__ sb) {
  const int y = blockIdx.y;
  if (y <= 2) {
    const float* __restrict__ src = (y == 0) ? x : (y == 1) ? Wq : Wk;
    f16* __restrict__ oh = (y == 0) ? xh : (y == 1) ? wqh : wkh;
    f16* __restrict__ ol = (y == 0) ? nullptr : (y == 1) ? wql : wkl;
    const int n4 = (y == 0) ? (4096 * 1024 / 4) : (1024 * 1024 / 4);
    for (int i = blockIdx.x * 256 + threadIdx.x; i < n4; i += 1024 * 256) {
      float4 f = ((const float4*)src)[i];
      f16x4v h, l;
      f16 hh, ll;
      split_f32(f.x, hh, ll); h[0] = hh; l[0] = ll;
      split_f32(f.y, hh, ll); h[1] = hh; l[1] = ll;
      split_f32(f.z, hh, ll); h[2] = hh; l[2] = ll;
      split_f32(f.w, hh, ll); h[3] = hh; l[3] = ll;
      ((f16x4v*)oh)[i] = h;
      if (y != 0) ((f16x4v*)ol)[i] = l;
    }
  } else if (y == 3) {
    if (blockIdx.x >= 256) return;
    __shared__ float sh[64][65];
    const int kb = (blockIdx.x >> 4) * 64, nb = (blockIdx.x & 15) * 64;
    const int t = threadIdx.x;
    const int r = t >> 2, c4 = (t & 3) * 16;
#pragma unroll
    for (int i = 0; i < 4; ++i) {
      float4 f = *(const float4*)&Wv[(size_t)(kb + r) * 1024 + nb + c4 + i * 4];
      sh[r][c4 + i * 4 + 0] = f.x;
      sh[r][c4 + i * 4 + 1] = f.y;
      sh[r][c4 + i * 4 + 2] = f.z;
      sh[r][c4 + i * 4 + 3] = f.w;
    }
    __syncthreads();
    const int n = t >> 2, ks = (t & 3) * 16;
    u16x8 h0, h1;
#pragma unroll
    for (int i = 0; i < 8; ++i) {
      h0[i] = __builtin_bit_cast(u16, (f16)sh[ks + i][n]);
      h1[i] = __builtin_bit_cast(u16, (f16)sh[ks + 8 + i][n]);
    }
    const size_t o = (size_t)(nb + n) * 1024 + kb + ks;
    *(u16x8*)&wvt[o] = h0;
    *(u16x8*)&wvt[o + 8] = h1;
  } else {
    if (blockIdx.x >= 512) return;
    const int z = blockIdx.x >> 8;
    const float* __restrict__ W = z ? Wk : Wq;
    float* __restrict__ o = z ? sb : sa;
    const int row = (blockIdx.x & 255) * 4 + (threadIdx.x >> 6);
    const int lane = threadIdx.x & 63;
    const float4* src = (const float4*)(W + (size_t)row * 1024);
    float s = 0.f;
#pragma unroll
    for (int i = 0; i < 4; ++i) {
      float4 f = src[lane + 64 * i];
      s += f.x + f.y + f.z + f.w;
    }
#pragma unroll
    for (int off = 1; off < 64; off <<= 1) s += __shfl_xor(s, off, 64);
    if (lane == 0) o[row] = s - 512.0f;
  }
}

// ---- prep: r = x*1, p = x*sa, q = x*sb ----
__global__ __launch_bounds__(256) void k_rpq(
    const float* __restrict__ x, const float* __restrict__ sa,
    const float* __restrict__ sb, float* __restrict__ rv,
    float* __restrict__ pv, float* __restrict__ qv) {
  const int row = blockIdx.x * 4 + (threadIdx.x >> 6);
  const int lane = threadIdx.x & 63;
  const float* xr = x + (size_t)row * 1024;
  float sr = 0.f, sp = 0.f, sq = 0.f;
#pragma unroll
  for (int i = 0; i < 4; ++i) {
    const int c = (lane + 64 * i) * 4;
    float4 f = *(const float4*)&xr[c];
    float4 a = *(const float4*)&sa[c];
    float4 b = *(const float4*)&sb[c];
    sr += f.x + f.y + f.z + f.w;
    sp += f.x * a.x + f.y * a.y + f.z * a.z + f.w * a.w;
    sq += f.x * b.x + f.y * b.y + f.z * b.z + f.w * b.w;
  }
#pragma unroll
  for (int off = 1; off < 64; off <<= 1) {
    sr += __shfl_xor(sr, off, 64);
    sp += __shfl_xor(sp, off, 64);
    sq += __shfl_xor(sq, off, 64);
  }
  if (lane == 0) {
    rv[row] = sr;
    pv[row] = sp;
    qv[row] = sq;
  }
}

// ---- T = xh·Mth^T (1-MFMA): 128x128 tile, 4 waves x (32 rows x 128 cols),
// BK=64, 2x32KB bufs (2 blocks/CU). Rows of 128B, slot swizzle ^=(row>>1)&7.
__global__ __launch_bounds__(256, 2) void k_tg(const f16* __restrict__ A,
                                               const f16* __restrict__ B,
                                               f16* __restrict__ Th) {
  char* smem = dsm;
  constexpr int K = 1024, nT = 16, BUF = 32768;
  const int tid = threadIdx.x;
  const int lane = tid & 63, wv = tid >> 6;  // 4 waves
  const int brow = blockIdx.x * 128, bcol = blockIdx.y * 128;
  const int srow8 = lane >> 3, scol8 = lane & 7;

  // 32 groups of 1KB (A g=0..15, B g=16..31); wave stages g=wv*8+half*4+j
  auto stageh = [&](int buf, int t, int half) {
    const int kt = t * 64;
    char* bb = smem + BUF * buf;
#pragma unroll
    for (int j = 0; j < 4; ++j) {
      const int g = wv * 8 + half * 4 + j;
      const int rg = g >> 4, gm = g & 15;
      const int r = gm * 8 + srow8;
      const f16* base = rg ? B : A;
      const int rowb = rg ? bcol : brow;
      const int sc = scol8 ^ ((r >> 1) & 7);
      gload16(base + (size_t)(rowb + r) * K + kt + 8 * sc,
              bb + rg * 16384 + gm * 1024);
    }
  };

  f32x16 acc[4] = {};  // [fn] — wave owns rows wv*32..+31, cols 0..127
  const int l31 = lane & 31, ch0 = lane >> 5;
  const int arow = wv * 32 + l31;

  stageh(0, 0, 0);
  stageh(0, 0, 1);

  for (int t = 0; t < nT; ++t) {
    const int cur = t & 1;
    const char* bb = smem + BUF * cur;
    const bool pre = t < nT - 1;
    if (pre) {
      stageh(cur ^ 1, t + 1, 0);
      __builtin_amdgcn_sched_barrier(0);
      asm volatile("s_waitcnt vmcnt(4)" ::: "memory");  // tile t's 8 landed
    } else {
      asm volatile("s_waitcnt vmcnt(0)" ::: "memory");
    }
    __builtin_amdgcn_sched_barrier(0);
    __builtin_amdgcn_s_barrier();  // RAW: tile t staging landed (all waves)
    __builtin_amdgcn_sched_barrier(0);

#pragma unroll
    for (int ks = 0; ks < 4; ++ks) {
      const int ch = ks * 2 + ch0;
      f16x8 a_h, b_h[4];
      a_h = *(const f16x8*)(bb + arow * 128 + 16 * (ch ^ ((arow >> 1) & 7)));
#pragma unroll
      for (int fn = 0; fn < 4; ++fn) {
        const int r = fn * 32 + l31;
        b_h[fn] = *(const f16x8*)(bb + 16384 + r * 128 +
                                  16 * (ch ^ ((r >> 1) & 7)));
      }
      if (ks == 1 && pre) stageh(cur ^ 1, t + 1, 1);
      asm volatile("s_waitcnt lgkmcnt(0)" ::: "memory");
      __builtin_amdgcn_sched_barrier(0);
      __builtin_amdgcn_s_setprio(1);
#pragma unroll
      for (int fn = 0; fn < 4; ++fn)
        acc[fn] = __builtin_amdgcn_mfma_f32_32x32x16_f16(a_h, b_h[fn], acc[fn],
                                                         0, 0, 0);
      __builtin_amdgcn_s_setprio(0);
    }
    __builtin_amdgcn_sched_barrier(0);
    __builtin_amdgcn_s_barrier();  // WAR: buf cur reads drained before reuse
  }

#pragma unroll
  for (int fn = 0; fn < 4; ++fn) {
    const int col = bcol + fn * 32 + l31;
#pragma unroll
    for (int j = 0; j < 16; ++j) {
      const int row = brow + wv * 32 + (j & 3) + 8 * (j >> 2) + 4 * ch0;
      Th[(size_t)row * 1024 + col] = (f16)acc[fn][j];
    }
  }
}

// ---- S-residual (1-MFMA) + deferred softmax; BK=64, 2x64KB buffers ----
__global__ __launch_bounds__(512, 1) void k_qkt(
    const f16* __restrict__ Ah, const f16* __restrict__ Bx,
    const float* __restrict__ rv, const float* __restrict__ pv,
    const float* __restrict__ qv, f16* __restrict__ Pt,
    float* __restrict__ mtile, float* __restrict__ tsum) {
  char* smem = dsm;
  constexpr int K = 1024, N = 4096, nT = 16, BUF = 65536;
  const int tid = threadIdx.x;
  const int lane = tid & 63, wv = tid >> 6;
  const int bid = blockIdx.x;
  const int wg = (bid & 7) * 32 + (bid >> 3);
  const int bx = wg >> 4, by = wg & 15;
  const int brow = bx * 256, bcol = by * 256;

  const int srow8 = lane >> 3;
  const int scol8 = lane & 7;

  auto stageh = [&](int buf, int t, int half) {
    const int kt = t * 64;
    char* bb = smem + BUF * buf;
#pragma unroll
    for (int j = 0; j < 4; ++j) {
      const int g = wv * 8 + half * 4 + j;
      const int rg = g >> 5, gm = g & 31;
      const int r = gm * 8 + srow8;
      const f16* base = rg ? Bx : Ah;
      const int rowb = rg ? bcol : brow;
      const int sc = scol8 ^ ((r >> 1) & 7);
      gload16(base + (size_t)(rowb + r) * K + kt + 8 * sc,
              bb + rg * 32768 + gm * 1024);
    }
  };

  f32x16 acc[8] = {};
  const int l31 = lane & 31, ch0 = lane >> 5;
  const int arow = wv * 32 + l31;

  stageh(0, 0, 0);
  stageh(0, 0, 1);

  for (int t = 0; t < nT; ++t) {
    const int cur = t & 1;
    const char* bb = smem + BUF * cur;
    const bool pre = t < nT - 1;
    if (pre) {
      stageh(cur ^ 1, t + 1, 0);
      __builtin_amdgcn_sched_barrier(0);
      asm volatile("s_waitcnt vmcnt(4)" ::: "memory");
    } else {
      asm volatile("s_waitcnt vmcnt(0)" ::: "memory");
    }
    __builtin_amdgcn_sched_barrier(0);
    __builtin_amdgcn_s_barrier();
    __builtin_amdgcn_sched_barrier(0);

#pragma unroll
    for (int ks = 0; ks < 4; ++ks) {
      const int ch = ks * 2 + ch0;
      f16x8 a_h, b_h[8];
      a_h = *(const f16x8*)(bb + arow * 128 + 16 * (ch ^ ((arow >> 1) & 7)));
#pragma unroll
      for (int fn = 0; fn < 8; ++fn) {
        const int r = fn * 32 + l31;
        b_h[fn] = *(const f16x8*)(bb + 32768 + r * 128 +
                                  16 * (ch ^ ((r >> 1) & 7)));
      }
      if (ks == 1 && pre) stageh(cur ^ 1, t + 1, 1);
      asm volatile("s_waitcnt lgkmcnt(0)" ::: "memory");
      __builtin_amdgcn_sched_barrier(0);
      __builtin_amdgcn_s_setprio(1);
#pragma unroll
      for (int fn = 0; fn < 8; ++fn)
        acc[fn] = __builtin_amdgcn_mfma_f32_32x32x16_f16(a_h, b_h[fn], acc[fn],
                                                         0, 0, 0);
      __builtin_amdgcn_s_setprio(0);
    }
    __builtin_amdgcn_sched_barrier(0);
    __builtin_amdgcn_s_barrier();
  }

  float rc[8], qc[8];
#pragma unroll
  for (int fn = 0; fn < 8; ++fn) {
    const int col = bcol + fn * 32 + l31;
    rc[fn] = rv[col];
    qc[fn] = qv[col];
  }
  const int rowbase = brow + wv * 32;
#pragma unroll
  for (int j = 0; j < 16; ++j) {
    const int rl = (j & 3) + 8 * (j >> 2) + 4 * ch0;
    const int row = rowbase + rl;
    const float rr = rv[row], pr = pv[row];
    float s[8];
    float m = -3.4e38f;
#pragma unroll
    for (int fn = 0; fn < 8; ++fn) {
      s[fn] = acc[fn][j] + 8.0f * rr * rc[fn] + (pr * rc[fn] + rr * qc[fn]) * 0.015625f;
      m = fmaxf(m, s[fn]);
    }
#pragma unroll
    for (int off = 1; off < 32; off <<= 1) m = fmaxf(m, __shfl_xor(m, off, 64));
    float sm = 0.f;
#pragma unroll
    for (int fn = 0; fn < 8; ++fn) {
      const float e = __expf(s[fn] - m);
      sm += e;
      Pt[(size_t)row * N + bcol + fn * 32 + l31] = (f16)e;
    }
#pragma unroll
    for (int off = 1; off < 32; off <<= 1) sm += __shfl_xor(sm, off, 64);
    if (l31 == 0) {
      mtile[row * 16 + by] = m;
      tsum[row * 16 + by] = sm;
    }
  }
}

// ---- PV: 128x128 block, 2 K-split quads, BK=64, 4x32KB bufs, scale folded.
__global__ __launch_bounds__(512, 2) void k_pvs(const f16* __restrict__ P,
                                                const f16* __restrict__ Vt,
                                                const float* __restrict__ mtile,
                                                const float* __restrict__ tsum,
                                                float* __restrict__ out) {
  char* smem = dsm;
  constexpr int K = 4096, BUF = 32768, NP = 32;
  const int tid = threadIdx.x;
  const int lane = tid & 63, wv = tid >> 6;
  const int qd = wv >> 2, wq = wv & 3;
  const int wr = wq >> 1, wc = wq & 1;
  const int bid = blockIdx.x;
  const int wg = (bid & 7) * 32 + (bid >> 3);
  const int bx = wg >> 3, by = wg & 7;
  const int brow = bx * 128, bcol = by * 128;

  float* sc_lds = (float*)(smem + 4 * BUF);
  if (tid < 128) {
    const int row = brow + tid;
    float mt[16], ts[16];
    float m = -3.4e38f;
#pragma unroll
    for (int t4 = 0; t4 < 4; ++t4) {
      float4 v = *(const float4*)&mtile[row * 16 + t4 * 4];
      float4 w = *(const float4*)&tsum[row * 16 + t4 * 4];
      mt[t4 * 4 + 0] = v.x; mt[t4 * 4 + 1] = v.y;
      mt[t4 * 4 + 2] = v.z; mt[t4 * 4 + 3] = v.w;
      ts[t4 * 4 + 0] = w.x; ts[t4 * 4 + 1] = w.y;
      ts[t4 * 4 + 2] = w.z; ts[t4 * 4 + 3] = w.w;
      m = fmaxf(m, fmaxf(fmaxf(v.x, v.y), fmaxf(v.z, v.w)));
    }
    float sum = 0.f;
#pragma unroll
    for (int t = 0; t < 16; ++t) sum += ts[t] * __expf(mt[t] - m);
    const float inv = 1.0f / sum;
#pragma unroll
    for (int t = 0; t < 16; ++t)
      sc_lds[t * 128 + tid] = __expf(mt[t] - m) * inv;
  }
  __syncthreads();

  const int srow8 = lane >> 3;
  const int scol8 = lane & 7;

  auto stage = [&](int t) {
    const int kt = t * 64;
    char* bb = smem + BUF * (t & 3);
#pragma unroll
    for (int j = 0; j < 4; ++j) {
      const int g = wv * 4 + j;
      const int rg = g >> 4, gm = g & 15;
      const int r = gm * 8 + srow8;
      const f16* base = rg ? Vt : P;
      const int rowb = rg ? bcol : brow;
      const int sc = scol8 ^ ((r >> 1) & 7);
      gload16(base + (size_t)(rowb + r) * K + kt + 8 * sc,
              bb + rg * 16384 + gm * 1024);
    }
  };

  f32x16 accp[2][2] = {};
  f32x16 accf[2][2] = {};
  const int l31 = lane & 31, ch0 = lane >> 5;
  const int ar0 = wr * 64 + l31;
  const int br0 = wc * 64 + l31;

  stage(0);
  stage(1);

  for (int p = 0; p < NP; ++p) {
    const bool pre = p < NP - 1;
    if (pre) {
      stage(2 * p + 2);
      __builtin_amdgcn_sched_barrier(0);
      asm volatile("s_waitcnt vmcnt(4)" ::: "memory");
    } else {
      asm volatile("s_waitcnt vmcnt(0)" ::: "memory");
    }
    __builtin_amdgcn_sched_barrier(0);
    __builtin_amdgcn_s_barrier();
    __builtin_amdgcn_sched_barrier(0);
    const char* bb = smem + BUF * ((2 * p + qd) & 3);
#pragma unroll
    for (int ks = 0; ks < 4; ++ks) {
      const int ch = ks * 2 + ch0;
      f16x8 a[2], b[2];
#pragma unroll
      for (int fm = 0; fm < 2; ++fm) {
        const int r = ar0 + fm * 32;
        a[fm] = *(const f16x8*)(bb + r * 128 + 16 * (ch ^ ((r >> 1) & 7)));
      }
#pragma unroll
      for (int fn = 0; fn < 2; ++fn) {
        const int r = br0 + fn * 32;
        b[fn] = *(const f16x8*)(bb + 16384 + r * 128 +
                                16 * (ch ^ ((r >> 1) & 7)));
      }
      if (ks == 0 && pre) stage(2 * p + 3);
      asm volatile("s_waitcnt lgkmcnt(0)" ::: "memory");
      __builtin_amdgcn_sched_barrier(0);
      __builtin_amdgcn_s_setprio(1);
#pragma unroll
      for (int fm = 0; fm < 2; ++fm)
#pragma unroll
        for (int fn = 0; fn < 2; ++fn)
          accp[fm][fn] = __builtin_amdgcn_mfma_f32_32x32x16_f16(
              a[fm], b[fn], accp[fm][fn], 0, 0, 0);
      __builtin_amdgcn_s_setprio(0);
    }
    if (p & 1) {
      const int tc = p >> 1;
#pragma unroll
      for (int fm = 0; fm < 2; ++fm)
#pragma unroll
        for (int fn = 0; fn < 2; ++fn)
#pragma unroll
          for (int j = 0; j < 16; ++j) {
            const int rloc =
                wr * 64 + fm * 32 + (j & 3) + 8 * (j >> 2) + 4 * ch0;
            accf[fm][fn][j] += sc_lds[tc * 128 + rloc] * accp[fm][fn][j];
            accp[fm][fn][j] = 0.0f;
          }
    }
    __builtin_amdgcn_sched_barrier(0);
    __builtin_amdgcn_s_barrier();
  }

  float* red = (float*)smem;
  if (qd == 1) {
#pragma unroll
    for (int fm = 0; fm < 2; ++fm)
#pragma unroll
      for (int fn = 0; fn < 2; ++fn)
#pragma unroll
        for (int j = 0; j < 16; ++j)
          red[wq * 4096 + (fm * 2 + fn) * 1024 + j * 64 + lane] =
              accf[fm][fn][j];
  }
  __syncthreads();
  if (qd == 0) {
#pragma unroll
    for (int fm = 0; fm < 2; ++fm)
#pragma unroll
      for (int fn = 0; fn < 2; ++fn)
#pragma unroll
        for (int j = 0; j < 16; ++j) {
          const float v = accf[fm][fn][j] +
                          red[wq * 4096 + (fm * 2 + fn) * 1024 + j * 64 + lane];
          const int row =
              brow + wr * 64 + fm * 32 + (j & 3) + 8 * (j >> 2) + 4 * ch0;
          const int col = bcol + wc * 64 + fn * 32 + l31;
          out[(size_t)row * 1024 + col] = v;
        }
  }
}

// ---- depth-3 pipelined BT-GEMM (Vt): C = A . B^T, f16 out ----
template <int K, int NBY>
__global__ __launch_bounds__(512, 1) void pipe_bt(const f16* __restrict__ A,
                                                  const f16* __restrict__ B,
                                                  f16* __restrict__ outh,
                                                  int ldo) {
  char* smem = dsm;
  constexpr int nT = K / 32, BUF = 16384;
  const int tid = threadIdx.x;
  const int lane = tid & 63, wv = tid >> 6;
  const int wm = wv >> 2, wn = wv & 3;
  const int bid = blockIdx.x;
  const int wg = (bid & 7) * 32 + (bid >> 3);
  const int bx = wg / NBY, by = wg % NBY;
  const int brow = bx * 128, bcol = by * 128;

  const int srow16 = lane >> 2;
  const int sslot = (lane & 3) ^ ((lane >> 3) & 3);
  const int sreg = wv >> 2;
  const f16* __restrict__ sbase = sreg ? B : A;
  const int rbase = sreg ? bcol : brow;

  auto stage = [&](int buf, int t) {
    const int kt = t * 32;
    char* bb = smem + BUF * buf + sreg * 8192;
#pragma unroll
    for (int j = 0; j < 2; ++j) {
      const int g = (wv & 3) * 2 + j;
      gload16(sbase + (size_t)(rbase + g * 16 + srow16) * K + kt + 8 * sslot,
              bb + g * 1024);
    }
  };

  f32x16 acc[2] = {};
  const int l31 = lane & 31, ch0 = lane >> 5;
  const int arow0 = wm * 64 + l31;
  const int brow0 = wn * 32 + l31;

  stage(0, 0);
  stage(1, 1);
  stage(2, 2);

  for (int t = 0; t < nT; ++t) {
    const int rem = nT - 1 - t;
    if (rem >= 3) stage((t + 3) & 3, t + 3);
    __builtin_amdgcn_sched_barrier(0);
    if (rem >= 3) {
      asm volatile("s_waitcnt vmcnt(6)" ::: "memory");
    } else if (rem == 2) {
      asm volatile("s_waitcnt vmcnt(4)" ::: "memory");
    } else if (rem == 1) {
      asm volatile("s_waitcnt vmcnt(2)" ::: "memory");
    } else {
      asm volatile("s_waitcnt vmcnt(0)" ::: "memory");
    }
    __builtin_amdgcn_sched_barrier(0);
    __builtin_amdgcn_s_barrier();
    __builtin_amdgcn_sched_barrier(0);
    const char* bb = smem + BUF * (t & 3);
#pragma unroll
    for (int ks = 0; ks < 2; ++ks) {
      const int ch = ks * 2 + ch0;
      f16x8 a_h[2], b_h;
#pragma unroll
      for (int fm = 0; fm < 2; ++fm) {
        const int r = arow0 + fm * 32;
        a_h[fm] = *(const f16x8*)(bb + r * 64 + 16 * (ch ^ ((r >> 1) & 3)));
      }
      b_h = *(const f16x8*)(bb + 8192 + brow0 * 64 +
                            16 * (ch ^ ((brow0 >> 1) & 3)));
      __builtin_amdgcn_sched_barrier(0);
      asm volatile("s_waitcnt lgkmcnt(0)" ::: "memory");
      __builtin_amdgcn_sched_barrier(0);
      __builtin_amdgcn_s_setprio(1);
#pragma unroll
      for (int fm = 0; fm < 2; ++fm)
        acc[fm] = __builtin_amdgcn_mfma_f32_32x32x16_f16(a_h[fm], b_h, acc[fm],
                                                         0, 0, 0);
      __builtin_amdgcn_s_setprio(0);
      __builtin_amdgcn_sched_barrier(0);
    }
    __builtin_amdgcn_s_barrier();
  }

#pragma unroll
  for (int fm = 0; fm < 2; ++fm) {
    const int col = bcol + wn * 32 + l31;
#pragma unroll
    for (int j = 0; j < 16; ++j) {
      const int row =
          brow + wm * 64 + fm * 32 + (j & 3) + 8 * (j >> 2) + 4 * ch0;
      outh[(size_t)row * ldo + col] = (f16)acc[fm][j];
    }
  }
}

// ---- generic BT-GEMM (m97-style), used for Mt only ----
template <int NM, int OUT>
__global__ __launch_bounds__(256) void gemm_bt(
    const f16* __restrict__ A, const f16* __restrict__ Al,
    const f16* __restrict__ B, const f16* __restrict__ Bl, int K,
    f16* __restrict__ oh, f16* __restrict__ ol, int ldo, float scale,
    const float* __restrict__ sav, const float* __restrict__ sbv) {
  f16* smem = (f16*)dsm;
  f16* tAh = smem;
  f16* tBh = smem + 8192;
  f16* tAl = smem + 16384;
  f16* tBl = smem + 24576;

  const int tid = threadIdx.x;
  const int lane = tid & 63, wid = tid >> 6;
  const int wr = wid >> 1, wc = wid & 1;
  const int brow = blockIdx.x * 128, bcol = blockIdx.y * 128;
  const int ar = lane & 15, k0 = (lane >> 4) * 8;
  const int crow = lane >> 3, ccol = (lane & 7) * 8;

  f32x4 acc[4][4] = {};
  const size_t aoff = (size_t)crow * K + ccol;

  for (int kt = 0; kt < K; kt += 64) {
    const f16* Ab = A + (size_t)brow * K + kt;
    const f16* Bb = B + (size_t)bcol * K + kt;
#pragma unroll
    for (int cc = 0; cc < 4; ++cc) {
      const int c = wid * 4 + cc;
      const size_t co = (size_t)c * 8 * K + aoff;
      gload16(Ab + co, tAh + c * 512);
      gload16(Bb + co, tBh + c * 512);
      if constexpr (NM >= 2) gload16(Al + (size_t)brow * K + kt + co, tAl + c * 512);
      if constexpr (NM == 3) gload16(Bl + (size_t)bcol * K + kt + co, tBl + c * 512);
    }
    __syncthreads();
#pragma unroll
    for (int ks = 0; ks < 2; ++ks) {
      f16x8 ah[4], bh[4], alv[4], blv[4];
#pragma unroll
      for (int m = 0; m < 4; ++m) {
        ah[m] = *(const f16x8*)&tAh[(wr * 64 + m * 16 + ar) * 64 + ks * 32 + k0];
        bh[m] = *(const f16x8*)&tBh[(wc * 64 + m * 16 + ar) * 64 + ks * 32 + k0];
        if constexpr (NM >= 2)
          alv[m] = *(const f16x8*)&tAl[(wr * 64 + m * 16 + ar) * 64 + ks * 32 + k0];
        if constexpr (NM == 3)
          blv[m] = *(const f16x8*)&tBl[(wc * 64 + m * 16 + ar) * 64 + ks * 32 + k0];
      }
#pragma unroll
      for (int m = 0; m < 4; ++m)
#pragma unroll
        for (int n = 0; n < 4; ++n) {
          acc[m][n] = __builtin_amdgcn_mfma_f32_16x16x32_f16(ah[m], bh[n], acc[m][n], 0, 0, 0);
          if constexpr (NM >= 2)
            acc[m][n] = __builtin_amdgcn_mfma_f32_16x16x32_f16(alv[m], bh[n], acc[m][n], 0, 0, 0);
          if constexpr (NM == 3)
            acc[m][n] = __builtin_amdgcn_mfma_f32_16x16x32_f16(ah[m], blv[n], acc[m][n], 0, 0, 0);
        }
    }
    __syncthreads();
  }

#pragma unroll
  for (int m = 0; m < 4; ++m)
#pragma unroll
    for (int n = 0; n < 4; ++n)
#pragma unroll
      for (int j = 0; j < 4; ++j) {
        const int row = brow + wr * 64 + m * 16 + (lane >> 4) * 4 + j;
        const int col = bcol + wc * 64 + n * 16 + ar;
        const size_t idx = (size_t)row * ldo + col;
        if constexpr (OUT == 1) {
          f16 h, l;
          split_f32(acc[m][n][j] * scale, h, l);
          oh[idx] = h;
          ol[idx] = l;
        } else if constexpr (OUT == 2) {
          oh[idx] = (f16)(acc[m][n][j] * scale);
        } else {  // OUT == 4: rank1-subtract, h only
          const float v =
              (acc[m][n][j] - 256.0f - 0.5f * sav[col] - 0.5f * sbv[row]) * scale;
          oh[idx] = (f16)v;
        }
      }
}

extern "C" void kernel_launch(void* const* d_in, const int* in_sizes, int n_in,
                              void* d_out, int out_size, void* d_ws,
                              size_t ws_size, hipStream_t stream) {
  const float* x = (const float*)d_in[0];
  const float* Wq = (const float*)d_in[1];
  const float* Wk = (const float*)d_in[2];
  const float* Wv = (const float*)d_in[3];
  float* out = (float*)d_out;
  char* ws = (char*)d_ws;
  const size_t MiB = 1u << 20;
  f16* xh = (f16*)(ws + 0 * MiB);
  f16* Th = (f16*)(ws + 16 * MiB);
  f16* Vt = (f16*)(ws + 32 * MiB);
  f16* Pt = (f16*)(ws + 40 * MiB);
  float* mtile = (float*)(ws + 72 * MiB);
  float* tsum = (float*)(ws + 73 * MiB);
  f16* Wqh = (f16*)(ws + 40 * MiB);
  f16* Wql = (f16*)(ws + 42 * MiB);
  f16* Wkh = (f16*)(ws + 44 * MiB);
  f16* Wkl = (f16*)(ws + 46 * MiB);
  f16* Mth = (f16*)(ws + 48 * MiB);
  f16* Wtvh = (f16*)(ws + 52 * MiB);
  float* sa = (float*)(ws + 54 * MiB);
  float* sb = (float*)(ws + 54 * MiB + 65536);
  float* rv = (float*)(ws + 8 * MiB);
  float* pv = (float*)(ws + 8 * MiB + 65536);
  float* qv = (float*)(ws + 8 * MiB + 131072);

  (void)hipFuncSetAttribute((const void*)k_qkt,
                            hipFuncAttributeMaxDynamicSharedMemorySize, 131072);
  (void)hipFuncSetAttribute((const void*)k_tg,
                            hipFuncAttributeMaxDynamicSharedMemorySize, 65536);
  (void)hipFuncSetAttribute((const void*)k_pvs,
                            hipFuncAttributeMaxDynamicSharedMemorySize, 139264);
  (void)hipFuncSetAttribute((const void*)pipe_bt<1024, 32>,
                            hipFuncAttributeMaxDynamicSharedMemorySize, 65536);

  k_prep<<<dim3(1024, 5), 256, 0, stream>>>(x, Wq, Wk, Wv, xh, Wqh, Wql, Wkh,
                                            Wkl, Wtvh, sa, sb);
  gemm_bt<3, 4><<<dim3(8, 8), 256, 65536, stream>>>(
      Wkh, Wkl, Wqh, Wql, 1024, Mth, nullptr, 1024, 0.03125f, sa, sb);
  // T = xh·(Mres/32)^T, 1-MFMA pipelined
  k_tg<<<dim3(32, 8), 256, 65536, stream>>>(xh, Mth, Th);
  pipe_bt<1024, 32><<<dim3(256), 512, 65536, stream>>>(Wtvh, xh, Vt, 4096);
  k_rpq<<<dim3(1024), 256, 0, stream>>>(x, sa, sb, rv, pv, qv);
  k_qkt<<<dim3(256), 512, 131072, stream>>>(Th, xh, rv, pv, qv, Pt, mtile,
                                            tsum);
  k_pvs<<<dim3(256), 512, 139264, stream>>>(Pt, Vt, mtile, tsum, out);
}